// Round 3
// baseline (301.332 us; speedup 1.0000x reference)
//
#include <hip/hip_runtime.h>

// DWT1D: x[32,64,16384] f32 -> out[32,192,8194] f32
// Planes: [0:64)=linear downsample, [64:128)=bior2.2 approx, [128:192)=detail.
//
// R3: pure-register streaming. Thread owns 2 consecutive k; window
// x[4p-4..4p+3] via two aligned float4 loads covers DWT taps AND both interp
// samples (i0 in [2k-4,2k], i1=i0+1) -> interp gather becomes cndmask selects.
// Stores: aligned float2 per plane, lane-contiguous (row stride 8194 forbids
// float4 alignment). No LDS, no barrier. R2 (~87us) paid LDS round-trips +
// 24 scalar store insts/thread; fill kernel shows 6.5 TB/s is reachable.

namespace {
constexpr int kN = 16384;
constexpr int kL = 8194;

__device__ __forceinline__ int symi(int j) {
    j = (j < 0) ? (-j - 1) : j;
    return (j >= kN) ? (2 * kN - 1 - j) : j;
}

__global__ __launch_bounds__(256) void dwt1d_kernel(const float* __restrict__ x,
                                                    float* __restrict__ out) {
    const int p = blockIdx.x * 256 + threadIdx.x;   // pair index, 0..4095
    const int row = blockIdx.y;                      // b*64 + c
    const float* __restrict__ xr = x + (size_t)row * kN;
    const int w0 = 4 * p - 4;                        // window start (16B-aligned for p>0)

    float v[8];
    if (p != 0) {
        const float4 A = *(const float4*)(xr + w0);
        const float4 B = *(const float4*)(xr + w0 + 4);
        v[0] = A.x; v[1] = A.y; v[2] = A.z; v[3] = A.w;
        v[4] = B.x; v[5] = B.y; v[6] = B.z; v[7] = B.w;
    } else {
#pragma unroll
        for (int i = 0; i < 8; ++i) v[i] = xr[symi(w0 + i)];
    }

    const float LO1 = -0.1767766952966369f;
    const float LO2 = 0.3535533905932738f;
    const float LO3 = 1.0606601717798212f;
    const float HI1 = 0.3535533905932738f;
    const float HI2 = -0.7071067811865476f;
    const float scale = 16384.0f / 8194.0f;

    float av[2], dv[2], sv[2];
#pragma unroll
    for (int j = 0; j < 2; ++j) {
        av[j] = LO3 * v[2 * j + 2] + LO2 * (v[2 * j + 1] + v[2 * j + 3]) +
                LO1 * (v[2 * j] + v[2 * j + 4]);
        dv[j] = HI2 * v[2 * j + 3] + HI1 * (v[2 * j + 2] + v[2 * j + 4]);

        const int k = 2 * p + j;
        float src = ((float)k + 0.5f) * scale - 0.5f;
        src = fminf(fmaxf(src, 0.0f), (float)(kN - 1));
        const int i0 = (int)floorf(src);
        const float w = src - (float)i0;
        const int t = i0 - w0 - 2 * j;               // in [0,4]
        const float x0 = (t == 0) ? v[2 * j]     : (t == 1) ? v[2 * j + 1]
                       : (t == 2) ? v[2 * j + 2] : (t == 3) ? v[2 * j + 3]
                                                            : v[2 * j + 4];
        const float x1 = (t == 0) ? v[2 * j + 1] : (t == 1) ? v[2 * j + 2]
                       : (t == 2) ? v[2 * j + 3] : (t == 3) ? v[2 * j + 4]
                                                            : v[2 * j + 5];
        sv[j] = x0 * (1.0f - w) + x1 * w;
    }

    const int b = row >> 6;
    const int c = row & 63;
    float* __restrict__ o0 = out + ((size_t)(b * 192 + c)) * kL;   // downsample
    float* __restrict__ o1 = o0 + (size_t)64 * kL;                 // approx
    float* __restrict__ o2 = o0 + (size_t)128 * kL;                // detail

    *(float2*)(o0 + 2 * p) = make_float2(sv[0], sv[1]);
    *(float2*)(o1 + 2 * p) = make_float2(av[0], av[1]);
    *(float2*)(o2 + 2 * p) = make_float2(dv[0], dv[1]);

    // tail: k = 8192, 8193 (beyond the 4096 pairs), scalar mirrored path
    if (p == 4095) {
#pragma unroll
        for (int kk = kN / 2; kk < kL; ++kk) {
            const float t0 = xr[symi(2 * kk - 4)];
            const float t1 = xr[symi(2 * kk - 3)];
            const float t2 = xr[symi(2 * kk - 2)];
            const float t3 = xr[symi(2 * kk - 1)];
            const float t4 = xr[symi(2 * kk)];
            const float a = LO3 * t2 + LO2 * (t1 + t3) + LO1 * (t0 + t4);
            const float d = HI2 * t3 + HI1 * (t2 + t4);
            float src = ((float)kk + 0.5f) * scale - 0.5f;
            src = fminf(fmaxf(src, 0.0f), (float)(kN - 1));
            const int i0 = (int)floorf(src);
            const int i1 = min(i0 + 1, kN - 1);
            const float w = src - (float)i0;
            o0[kk] = xr[i0] * (1.0f - w) + xr[i1] * w;
            o1[kk] = a;
            o2[kk] = d;
        }
    }
}
}  // namespace

extern "C" void kernel_launch(void* const* d_in, const int* in_sizes, int n_in,
                              void* d_out, int out_size, void* d_ws, size_t ws_size,
                              hipStream_t stream) {
    const float* x = (const float*)d_in[0];
    float* out = (float*)d_out;
    dim3 grid(16, 32 * 64);   // 4096 pairs/row in 16 blocks; 2048 rows
    dwt1d_kernel<<<grid, dim3(256), 0, stream>>>(x, out);
}